// Round 4
// baseline (2600.558 us; speedup 1.0000x reference)
//
#include <hip/hip_runtime.h>

// SumGCNEncoder: NU=NI=100000, DIN=DOUT=128, NS=5, E=500000
#define R_     100000
#define NSUP   5
#define EDGES  500000
#define D_     128
#define ND     (NSUP * D_)          // 640
#define NEDGE_TOT (NSUP * EDGES)    // 2,500,000 (per side)

#define PROWS  256                  // rows per coarse partition
#define PPS    ((R_ + PROWS - 1) / PROWS)   // 391 partitions per support
#define NPART  (NSUP * PPS)         // 1955
#define CAP    2048                 // max edges per partition (mean 1280, ~21 sigma headroom)

#define CHUNK  51200                // rows per S/gemm chunk (200 partitions)
#define PR_CH0 200                  // partitions-per-support in chunk 0
#define PR_CH1 (PPS - PR_CH0)       // 191 in chunk 1

using short8 = __attribute__((ext_vector_type(8))) short;
using f32x4  = __attribute__((ext_vector_type(4))) float;

static __device__ __forceinline__ float bf2f_lo(unsigned p) { return __uint_as_float(p << 16); }
static __device__ __forceinline__ float bf2f_hi(unsigned p) { return __uint_as_float(p & 0xffff0000u); }
static __device__ __forceinline__ unsigned short f2bf(float x) {
    unsigned u = __float_as_uint(x);
    return (unsigned short)((u + 0x7fffu + ((u >> 16) & 1u)) >> 16);  // RNE
}

// ---------------------------------------------------------------------------
// BT[o][k], k=i*128+d: cumulative weight sum, transposed. bf16 [128][640]
__global__ __launch_bounds__(256) void build_bt(const float* __restrict__ w,
                                                unsigned short* __restrict__ bt) {
    int t = blockIdx.x * 256 + threadIdx.x;
    if (t >= D_ * ND) return;
    int o = t / ND;
    int kk = t - o * ND;
    int i = kk >> 7, d = kk & 127;
    float s = 0.f;
    for (int j = 0; j <= i; j++) s += w[(d * D_ + o) * NSUP + j];
    bt[t] = f2bf(s);
}

// fp32 [R_,128] -> bf16 table
__global__ __launch_bounds__(256) void conv_src(const float* __restrict__ src,
                                                unsigned short* __restrict__ dst) {
    int t = blockIdx.x * 256 + threadIdx.x;
    if (t * 4 >= R_ * D_) return;
    float4 v = *(const float4*)(src + t * 4);
    ushort4 o;
    o.x = f2bf(v.x); o.y = f2bf(v.y); o.z = f2bf(v.z); o.w = f2bf(v.w);
    *(ushort4*)(dst + t * 4) = o;
}

// ---------------------------------------------------------------------------
// Coarse binning: partition p = i*PPS + (row>>8)
__global__ __launch_bounds__(256) void ccount_k(const int* __restrict__ rows,
                                                int* __restrict__ cc) {
    int t = blockIdx.x * 256 + threadIdx.x;
    if (t >= NEDGE_TOT) return;
    int i = t / EDGES;
    atomicAdd(&cc[i * PPS + (rows[t] >> 8)], 1);
}

// exclusive scan over cc[NPART] -> cstart[NPART+1], copy to ccur
__global__ __launch_bounds__(1024) void cscan_k(const int* __restrict__ cc,
                                                int* __restrict__ cstart,
                                                int* __restrict__ ccur) {
    __shared__ int sh[1024];
    int t = threadIdx.x;
    int a = (2 * t     < NPART) ? cc[2 * t]     : 0;
    int b = (2 * t + 1 < NPART) ? cc[2 * t + 1] : 0;
    int s = a + b;
    sh[t] = s;
    __syncthreads();
    for (int off = 1; off < 1024; off <<= 1) {
        int v = (t >= off) ? sh[t - off] : 0;
        __syncthreads();
        sh[t] += v;
        __syncthreads();
    }
    int ex = sh[t] - s;
    if (2 * t < NPART)     { cstart[2 * t] = ex;         ccur[2 * t] = ex; }
    if (2 * t + 1 < NPART) { cstart[2 * t + 1] = ex + a; ccur[2 * t + 1] = ex + a; }
    if (t == 1023) cstart[NPART] = sh[1023];
}

// bin edges into partition-contiguous regions; pack (col | rowlow<<17, val)
__global__ __launch_bounds__(256) void cfill_k(const int* __restrict__ rows,
                                               const int* __restrict__ cols,
                                               const float* __restrict__ vals,
                                               int* __restrict__ ccur,
                                               uint2* __restrict__ cedge) {
    int t = blockIdx.x * 256 + threadIdx.x;
    if (t >= NEDGE_TOT) return;
    int i = t / EDGES;
    int row = rows[t];
    int p = i * PPS + (row >> 8);
    int pos = atomicAdd(&ccur[p], 1);
    uint2 e;
    e.x = (unsigned)cols[t] | ((unsigned)(row & 255) << 17);
    e.y = __float_as_uint(vals[t]);
    cedge[pos] = e;
}

// ---------------------------------------------------------------------------
// Fused fine-CSR (in LDS) + gather. One block per partition.
// Grid covers supports x [pr0, pr0+npc). S: bf16 [CHUNK rows, 640].
__global__ __launch_bounds__(256) void gather_fused(const int* __restrict__ cstart,
                                                    const uint2* __restrict__ cedge,
                                                    const unsigned short* __restrict__ srcbf,
                                                    unsigned short* __restrict__ S,
                                                    int pr0, int npc) {
    __shared__ uint2 eds[CAP];      // 16 KB
    __shared__ int rcnt[PROWS];     // 1 KB (count, then cursor)
    __shared__ int rsc[PROWS];      // 1 KB (inclusive scan)

    int q = blockIdx.x;
    int i = q / npc;
    int pr = pr0 + (q - i * npc);
    int p = i * PPS + pr;
    int st = cstart[p];
    int n = cstart[p + 1] - st;
    if (n > CAP) n = CAP;           // statistically impossible; guards LDS

    int tid = threadIdx.x;
    rcnt[tid] = 0;
    __syncthreads();

    // pass 1: count rows
    for (int e = tid; e < n; e += 256) {
        uint2 E = cedge[st + e];
        atomicAdd(&rcnt[(E.x >> 17) & 255], 1);
    }
    __syncthreads();

    // inclusive scan of rcnt -> rsc
    int v = rcnt[tid];
    rsc[tid] = v;
    __syncthreads();
    for (int off = 1; off < 256; off <<= 1) {
        int u = (tid >= off) ? rsc[tid - off] : 0;
        __syncthreads();
        rsc[tid] += u;
        __syncthreads();
    }
    rcnt[tid] = rsc[tid] - v;       // exclusive start as cursor
    __syncthreads();

    // pass 2: reorder into LDS (cedge range is L2-hot from pass 1)
    for (int e = tid; e < n; e += 256) {
        uint2 E = cedge[st + e];
        int pos = atomicAdd(&rcnt[(E.x >> 17) & 255], 1);
        eds[pos] = E;
    }
    __syncthreads();

    // process: wave w handles rows w, w+4, ...
    int wid = tid >> 6, lane = tid & 63;
    int rlbase = (pr - pr0) << 8;
    for (int r = wid; r < PROWS; r += 4) {
        int s  = r ? rsc[r - 1] : 0;
        int e2 = rsc[r];
        float a0 = 0.f, a1 = 0.f;
        int e = s;
        for (; e + 1 < e2; e += 2) {
            uint2 E0 = eds[e], E1 = eds[e + 1];
            unsigned p0 = *(const unsigned*)(srcbf + (size_t)(E0.x & 0x1FFFFu) * D_ + lane * 2);
            unsigned p1 = *(const unsigned*)(srcbf + (size_t)(E1.x & 0x1FFFFu) * D_ + lane * 2);
            float v0 = __uint_as_float(E0.y), v1 = __uint_as_float(E1.y);
            a0 += v0 * bf2f_lo(p0); a1 += v0 * bf2f_hi(p0);
            a0 += v1 * bf2f_lo(p1); a1 += v1 * bf2f_hi(p1);
        }
        if (e < e2) {
            uint2 E = eds[e];
            unsigned pk = *(const unsigned*)(srcbf + (size_t)(E.x & 0x1FFFFu) * D_ + lane * 2);
            float vv = __uint_as_float(E.y);
            a0 += vv * bf2f_lo(pk); a1 += vv * bf2f_hi(pk);
        }
        unsigned o = ((unsigned)f2bf(a1) << 16) | (unsigned)f2bf(a0);
        *(unsigned*)(S + (size_t)(rlbase + r) * ND + i * D_ + lane * 2) = o;
    }
}

// ---------------------------------------------------------------------------
// out[row0+l, o] = relu(sum_k S[l,k]*BT[o,k]); 32 rows/wave, MFMA 16x16x32.
__global__ __launch_bounds__(256) void gemm_relu(const unsigned short* __restrict__ S,
                                                 const unsigned short* __restrict__ BT,
                                                 float* __restrict__ out,
                                                 int row0, int cr) {
    int wid = threadIdx.x >> 6, lane = threadIdx.x & 63;
    int wv = blockIdx.x * 4 + wid;
    int l0 = wv * 32;
    if (l0 >= cr) return;
    int r = lane & 15, q = lane >> 4;

    f32x4 acc0[8], acc1[8];
#pragma unroll
    for (int nt = 0; nt < 8; nt++) {
        acc0[nt] = (f32x4){0.f, 0.f, 0.f, 0.f};
        acc1[nt] = (f32x4){0.f, 0.f, 0.f, 0.f};
    }

    const unsigned short* a0p = S + (size_t)(l0 + r) * ND + q * 8;
    const unsigned short* a1p = S + (size_t)(l0 + 16 + r) * ND + q * 8;
    for (int c = 0; c < 20; c++) {
        short8 a0 = *(const short8*)(a0p + c * 32);
        short8 a1 = *(const short8*)(a1p + c * 32);
#pragma unroll
        for (int nt = 0; nt < 8; nt++) {
            short8 b = *(const short8*)(BT + (size_t)(nt * 16 + r) * ND + q * 8 + c * 32);
            acc0[nt] = __builtin_amdgcn_mfma_f32_16x16x32_bf16(a0, b, acc0[nt], 0, 0, 0);
            acc1[nt] = __builtin_amdgcn_mfma_f32_16x16x32_bf16(a1, b, acc1[nt], 0, 0, 0);
        }
    }

#pragma unroll
    for (int nt = 0; nt < 8; nt++) {
#pragma unroll
        for (int rr = 0; rr < 4; rr++) {
            int col = nt * 16 + r;
            int l = l0 + q * 4 + rr;
            if (l < cr) {
                float v = acc0[nt][rr];
                out[(size_t)(row0 + l) * D_ + col] = v > 0.f ? v : 0.f;
            }
            l += 16;
            if (l < cr) {
                float v = acc1[nt][rr];
                out[(size_t)(row0 + l) * D_ + col] = v > 0.f ? v : 0.f;
            }
        }
    }
}

// ---------------------------------------------------------------------------
extern "C" void kernel_launch(void* const* d_in, const int* in_sizes, int n_in,
                              void* d_out, int out_size, void* d_ws, size_t ws_size,
                              hipStream_t stream) {
    const float* user_in = (const float*)d_in[0];
    const float* item_in = (const float*)d_in[1];
    const float* weight  = (const float*)d_in[2];
    const int* u_rows = (const int*)d_in[3];
    const int* u_cols = (const int*)d_in[4];
    const float* u_vals = (const float*)d_in[5];
    const int* i_rows = (const int*)d_in[6];
    const int* i_cols = (const int*)d_in[7];
    const float* i_vals = (const float*)d_in[8];
    float* out = (float*)d_out;

    // ws layout (bytes), total ~111.3 MB
    char* ws = (char*)d_ws;
    unsigned short* S    = (unsigned short*)(ws);                 // 51200*640*2 = 65,536,000
    unsigned short* BT   = (unsigned short*)(ws + 65536000);      // 163,840
    unsigned short* srcb = (unsigned short*)(ws + 65699840);      // 25,600,000
    int*   ccount = (int*)  (ws + 91299840);                      // pad 8,192
    int*   cstart = (int*)  (ws + 91308032);                      // pad 8,192
    int*   ccur   = (int*)  (ws + 91316224);                      // pad 8,192
    uint2* cedge  = (uint2*)(ws + 91324416);                      // 20,000,000 -> ends 111,324,416

    build_bt<<<(D_ * ND + 255) / 256, 256, 0, stream>>>(weight, BT);

    const int nb_edges = (NEDGE_TOT + 255) / 256;        // 9766
    const int nb_conv  = (R_ * D_ / 4 + 255) / 256;      // 12500

    for (int side = 0; side < 2; side++) {
        const int* rows = side ? i_rows : u_rows;
        const int* cols = side ? i_cols : u_cols;
        const float* vals = side ? i_vals : u_vals;
        const float* src  = side ? user_in : item_in;    // user_hidden gathers item feats
        float* out_side = out + (size_t)side * R_ * D_;

        conv_src<<<nb_conv, 256, 0, stream>>>(src, srcb);
        hipMemsetAsync(ccount, 0, NPART * sizeof(int), stream);
        ccount_k<<<nb_edges, 256, 0, stream>>>(rows, ccount);
        cscan_k<<<1, 1024, 0, stream>>>(ccount, cstart, ccur);
        cfill_k<<<nb_edges, 256, 0, stream>>>(rows, cols, vals, ccur, cedge);

        for (int ch = 0; ch < 2; ch++) {
            int pr0 = ch ? PR_CH0 : 0;
            int npc = ch ? PR_CH1 : PR_CH0;
            int row0 = pr0 << 8;
            int cr = ch ? (R_ - CHUNK) : CHUNK;          // 48800 / 51200
            gather_fused<<<NSUP * npc, 256, 0, stream>>>(cstart, cedge, srcb, S, pr0, npc);
            int nbg = ((cr + 31) / 32 + 3) / 4;
            gemm_relu<<<nbg, 256, 0, stream>>>(S, BT, out_side, row0, cr);
        }
    }
}

// Round 5
// 910.490 us; speedup vs baseline: 2.8562x; 2.8562x over previous
//
#include <hip/hip_runtime.h>

// SumGCNEncoder: NU=NI=100000, DIN=DOUT=128, NS=5, E=500000
#define R_     100000
#define NSUP   5
#define EDGES  500000
#define D_     128
#define ND     (NSUP * D_)          // 640
#define NEDGE_TOT (NSUP * EDGES)    // 2,500,000 (per side)

#define PROWS  256                  // rows per partition
#define PPS    ((R_ + PROWS - 1) / PROWS)   // 391 partitions per support
#define NPART  (NSUP * PPS)         // 1955
#define CAP    2048                 // max edges per partition (mean 1279, ~21 sigma)

#define NB_SORT 128                 // histogram/fill blocks
#define SEG    ((NEDGE_TOT + NB_SORT - 1) / NB_SORT)   // 19532 edges per block

#define CHUNK  51200                // rows per S/gemm chunk (200 partitions)
#define PR_CH0 200
#define PR_CH1 (PPS - PR_CH0)       // 191

using short8 = __attribute__((ext_vector_type(8))) short;
using f32x4  = __attribute__((ext_vector_type(4))) float;

static __device__ __forceinline__ float bf2f_lo(unsigned p) { return __uint_as_float(p << 16); }
static __device__ __forceinline__ float bf2f_hi(unsigned p) { return __uint_as_float(p & 0xffff0000u); }
static __device__ __forceinline__ unsigned short f2bf(float x) {
    unsigned u = __float_as_uint(x);
    return (unsigned short)((u + 0x7fffu + ((u >> 16) & 1u)) >> 16);  // RNE
}

// ---------------------------------------------------------------------------
// BT[o][k], k=i*128+d: cumulative weight sum, transposed. bf16 [128][640]
__global__ __launch_bounds__(256) void build_bt(const float* __restrict__ w,
                                                unsigned short* __restrict__ bt) {
    int t = blockIdx.x * 256 + threadIdx.x;
    if (t >= D_ * ND) return;
    int o = t / ND;
    int kk = t - o * ND;
    int i = kk >> 7, d = kk & 127;
    float s = 0.f;
    for (int j = 0; j <= i; j++) s += w[(d * D_ + o) * NSUP + j];
    bt[t] = f2bf(s);
}

// fp32 [R_,128] -> bf16 table
__global__ __launch_bounds__(256) void conv_src(const float* __restrict__ src,
                                                unsigned short* __restrict__ dst) {
    int t = blockIdx.x * 256 + threadIdx.x;
    if (t * 4 >= R_ * D_) return;
    float4 v = *(const float4*)(src + t * 4);
    ushort4 o;
    o.x = f2bf(v.x); o.y = f2bf(v.y); o.z = f2bf(v.z); o.w = f2bf(v.w);
    *(ushort4*)(dst + t * 4) = o;
}

// ---------------------------------------------------------------------------
// Counting sort, phase 1: per-block LDS histogram over NPART bins.
__global__ __launch_bounds__(512) void hist_k(const int* __restrict__ rows,
                                              int* __restrict__ hist) {
    __shared__ int h[NPART];
    for (int j = threadIdx.x; j < NPART; j += 512) h[j] = 0;
    __syncthreads();
    int b = blockIdx.x;
    int t1 = b * SEG + SEG;
    if (t1 > NEDGE_TOT) t1 = NEDGE_TOT;
    for (int t = b * SEG + threadIdx.x; t < t1; t += 512) {
        int i = t / EDGES;
        atomicAdd(&h[i * PPS + (rows[t] >> 8)], 1);
    }
    __syncthreads();
    for (int j = threadIdx.x; j < NPART; j += 512) hist[b * NPART + j] = h[j];
}

// phase 2: per-bin exclusive scan over the NB_SORT blocks (in place) + totals
__global__ __launch_bounds__(NB_SORT) void colscan_k(int* __restrict__ hist,
                                                     int* __restrict__ btot) {
    __shared__ int sh[NB_SORT];
    int bin = blockIdx.x;
    int t = threadIdx.x;
    int v = hist[t * NPART + bin];
    sh[t] = v;
    __syncthreads();
    for (int off = 1; off < NB_SORT; off <<= 1) {
        int u = (t >= off) ? sh[t - off] : 0;
        __syncthreads();
        sh[t] += u;
        __syncthreads();
    }
    hist[t * NPART + bin] = sh[t] - v;   // exclusive within column
    if (t == NB_SORT - 1) btot[bin] = sh[NB_SORT - 1];
}

// phase 3: exclusive scan of bin totals -> binstart[NPART+1]
__global__ __launch_bounds__(1024) void bscan_k(const int* __restrict__ btot,
                                                int* __restrict__ binstart) {
    __shared__ int sh[1024];
    int t = threadIdx.x;
    int a = (2 * t     < NPART) ? btot[2 * t]     : 0;
    int b = (2 * t + 1 < NPART) ? btot[2 * t + 1] : 0;
    int s = a + b;
    sh[t] = s;
    __syncthreads();
    for (int off = 1; off < 1024; off <<= 1) {
        int v = (t >= off) ? sh[t - off] : 0;
        __syncthreads();
        sh[t] += v;
        __syncthreads();
    }
    int ex = sh[t] - s;
    if (2 * t < NPART)     binstart[2 * t] = ex;
    if (2 * t + 1 < NPART) binstart[2 * t + 1] = ex + a;
    if (t == 1023) binstart[NPART] = sh[1023];
}

// phase 4: place edges via LDS cursors (no global atomics).
// pack (col | rowlow<<17, val)
__global__ __launch_bounds__(512) void fillsort_k(const int* __restrict__ rows,
                                                  const int* __restrict__ cols,
                                                  const float* __restrict__ vals,
                                                  const int* __restrict__ hist,
                                                  const int* __restrict__ binstart,
                                                  uint2* __restrict__ cedge) {
    __shared__ int cur[NPART];
    int b = blockIdx.x;
    for (int j = threadIdx.x; j < NPART; j += 512)
        cur[j] = binstart[j] + hist[b * NPART + j];
    __syncthreads();
    int t1 = b * SEG + SEG;
    if (t1 > NEDGE_TOT) t1 = NEDGE_TOT;
    for (int t = b * SEG + threadIdx.x; t < t1; t += 512) {
        int i = t / EDGES;
        int row = rows[t];
        int bin = i * PPS + (row >> 8);
        int pos = atomicAdd(&cur[bin], 1);
        uint2 e;
        e.x = (unsigned)cols[t] | ((unsigned)(row & 255) << 17);
        e.y = __float_as_uint(vals[t]);
        cedge[pos] = e;
    }
}

// ---------------------------------------------------------------------------
// Fused fine-CSR (in LDS) + gather. One block per partition.
__global__ __launch_bounds__(256) void gather_fused(const int* __restrict__ cstart,
                                                    const uint2* __restrict__ cedge,
                                                    const unsigned short* __restrict__ srcbf,
                                                    unsigned short* __restrict__ S,
                                                    int pr0, int npc) {
    __shared__ uint2 eds[CAP];      // 16 KB
    __shared__ int rcnt[PROWS];     // 1 KB
    __shared__ int rsc[PROWS];      // 1 KB

    int q = blockIdx.x;
    int i = q / npc;
    int pr = pr0 + (q - i * npc);
    int p = i * PPS + pr;
    int st = cstart[p];
    int n = cstart[p + 1] - st;
    if (n > CAP) n = CAP;

    int tid = threadIdx.x;
    rcnt[tid] = 0;
    __syncthreads();

    for (int e = tid; e < n; e += 256) {
        uint2 E = cedge[st + e];
        atomicAdd(&rcnt[(E.x >> 17) & 255], 1);
    }
    __syncthreads();

    int v = rcnt[tid];
    rsc[tid] = v;
    __syncthreads();
    for (int off = 1; off < 256; off <<= 1) {
        int u = (tid >= off) ? rsc[tid - off] : 0;
        __syncthreads();
        rsc[tid] += u;
        __syncthreads();
    }
    rcnt[tid] = rsc[tid] - v;
    __syncthreads();

    for (int e = tid; e < n; e += 256) {
        uint2 E = cedge[st + e];
        int pos = atomicAdd(&rcnt[(E.x >> 17) & 255], 1);
        eds[pos] = E;
    }
    __syncthreads();

    int wid = tid >> 6, lane = tid & 63;
    int rlbase = (pr - pr0) << 8;
    for (int r = wid; r < PROWS; r += 4) {
        int s  = r ? rsc[r - 1] : 0;
        int e2 = rsc[r];
        float a0 = 0.f, a1 = 0.f;
        int e = s;
        for (; e + 1 < e2; e += 2) {
            uint2 E0 = eds[e], E1 = eds[e + 1];
            unsigned p0 = *(const unsigned*)(srcbf + (size_t)(E0.x & 0x1FFFFu) * D_ + lane * 2);
            unsigned p1 = *(const unsigned*)(srcbf + (size_t)(E1.x & 0x1FFFFu) * D_ + lane * 2);
            float v0 = __uint_as_float(E0.y), v1 = __uint_as_float(E1.y);
            a0 += v0 * bf2f_lo(p0); a1 += v0 * bf2f_hi(p0);
            a0 += v1 * bf2f_lo(p1); a1 += v1 * bf2f_hi(p1);
        }
        if (e < e2) {
            uint2 E = eds[e];
            unsigned pk = *(const unsigned*)(srcbf + (size_t)(E.x & 0x1FFFFu) * D_ + lane * 2);
            float vv = __uint_as_float(E.y);
            a0 += vv * bf2f_lo(pk); a1 += vv * bf2f_hi(pk);
        }
        unsigned o = ((unsigned)f2bf(a1) << 16) | (unsigned)f2bf(a0);
        *(unsigned*)(S + (size_t)(rlbase + r) * ND + i * D_ + lane * 2) = o;
    }
}

// ---------------------------------------------------------------------------
// out[row0+l, o] = relu(sum_k S[l,k]*BT[o,k]); 32 rows/wave, MFMA 16x16x32.
__global__ __launch_bounds__(256) void gemm_relu(const unsigned short* __restrict__ S,
                                                 const unsigned short* __restrict__ BT,
                                                 float* __restrict__ out,
                                                 int row0, int cr) {
    int wid = threadIdx.x >> 6, lane = threadIdx.x & 63;
    int wv = blockIdx.x * 4 + wid;
    int l0 = wv * 32;
    if (l0 >= cr) return;
    int r = lane & 15, q = lane >> 4;

    f32x4 acc0[8], acc1[8];
#pragma unroll
    for (int nt = 0; nt < 8; nt++) {
        acc0[nt] = (f32x4){0.f, 0.f, 0.f, 0.f};
        acc1[nt] = (f32x4){0.f, 0.f, 0.f, 0.f};
    }

    const unsigned short* a0p = S + (size_t)(l0 + r) * ND + q * 8;
    const unsigned short* a1p = S + (size_t)(l0 + 16 + r) * ND + q * 8;
    for (int c = 0; c < 20; c++) {
        short8 a0 = *(const short8*)(a0p + c * 32);
        short8 a1 = *(const short8*)(a1p + c * 32);
#pragma unroll
        for (int nt = 0; nt < 8; nt++) {
            short8 b = *(const short8*)(BT + (size_t)(nt * 16 + r) * ND + q * 8 + c * 32);
            acc0[nt] = __builtin_amdgcn_mfma_f32_16x16x32_bf16(a0, b, acc0[nt], 0, 0, 0);
            acc1[nt] = __builtin_amdgcn_mfma_f32_16x16x32_bf16(a1, b, acc1[nt], 0, 0, 0);
        }
    }

#pragma unroll
    for (int nt = 0; nt < 8; nt++) {
#pragma unroll
        for (int rr = 0; rr < 4; rr++) {
            int col = nt * 16 + r;
            int l = l0 + q * 4 + rr;
            if (l < cr) {
                float v = acc0[nt][rr];
                out[(size_t)(row0 + l) * D_ + col] = v > 0.f ? v : 0.f;
            }
            l += 16;
            if (l < cr) {
                float v = acc1[nt][rr];
                out[(size_t)(row0 + l) * D_ + col] = v > 0.f ? v : 0.f;
            }
        }
    }
}

// ---------------------------------------------------------------------------
extern "C" void kernel_launch(void* const* d_in, const int* in_sizes, int n_in,
                              void* d_out, int out_size, void* d_ws, size_t ws_size,
                              hipStream_t stream) {
    const float* user_in = (const float*)d_in[0];
    const float* item_in = (const float*)d_in[1];
    const float* weight  = (const float*)d_in[2];
    const int* u_rows = (const int*)d_in[3];
    const int* u_cols = (const int*)d_in[4];
    const float* u_vals = (const float*)d_in[5];
    const int* i_rows = (const int*)d_in[6];
    const int* i_cols = (const int*)d_in[7];
    const float* i_vals = (const float*)d_in[8];
    float* out = (float*)d_out;

    // ws layout (bytes), total ~112.3 MB
    char* ws = (char*)d_ws;
    unsigned short* S    = (unsigned short*)(ws);                 // 51200*640*2 = 65,536,000
    unsigned short* BT   = (unsigned short*)(ws + 65536000);      // 163,840
    unsigned short* srcb = (unsigned short*)(ws + 65699840);      // 25,600,000 -> 91,299,840
    int*   hist     = (int*)  (ws + 91299840);                    // 128*1955*4 = 1,000,960
    int*   btot     = (int*)  (ws + 92300800);                    // 8,192
    int*   binstart = (int*)  (ws + 92308992);                    // 8,192
    uint2* cedge    = (uint2*)(ws + 92317184);                    // 20,000,000 -> 112,317,184

    build_bt<<<(D_ * ND + 255) / 256, 256, 0, stream>>>(weight, BT);

    const int nb_conv = (R_ * D_ / 4 + 255) / 256;   // 12500

    for (int side = 0; side < 2; side++) {
        const int* rows = side ? i_rows : u_rows;
        const int* cols = side ? i_cols : u_cols;
        const float* vals = side ? i_vals : u_vals;
        const float* src  = side ? user_in : item_in;  // user_hidden gathers item feats
        float* out_side = out + (size_t)side * R_ * D_;

        conv_src<<<nb_conv, 256, 0, stream>>>(src, srcb);
        hist_k<<<NB_SORT, 512, 0, stream>>>(rows, hist);
        colscan_k<<<NPART, NB_SORT, 0, stream>>>(hist, btot);
        bscan_k<<<1, 1024, 0, stream>>>(btot, binstart);
        fillsort_k<<<NB_SORT, 512, 0, stream>>>(rows, cols, vals, hist, binstart, cedge);

        for (int ch = 0; ch < 2; ch++) {
            int pr0 = ch ? PR_CH0 : 0;
            int npc = ch ? PR_CH1 : PR_CH0;
            int row0 = pr0 << 8;
            int cr = ch ? (R_ - CHUNK) : CHUNK;      // 48800 / 51200
            gather_fused<<<NSUP * npc, 256, 0, stream>>>(binstart, cedge, srcb, S, pr0, npc);
            int nbg = ((cr + 31) / 32 + 3) / 4;
            gemm_relu<<<nbg, 256, 0, stream>>>(S, BT, out_side, row0, cr);
        }
    }
}